// Round 4
// baseline (2069.918 us; speedup 1.0000x reference)
//
#include <hip/hip_runtime.h>
#include <cstdint>
#include <cstddef>

// ---------------------------------------------------------------------------
// AlphaNet: features -> BN -> conv(1x3,16) -> relu -> fc1(43200->512) -> relu
//          -> fc2(512->128) -> sigmoid -> fc3(128->1)
// R13: GEMM re-shaped for staging-traffic (the measured ~5.5 TB/s delivery
//   ceiling, invariant across R9/R10/R12 schedules):
//   - 256M x 512N tile (nt=1): A staged ONCE (177 MB, was 354).
//   - 16 waves (1024 thr), BK=32, depth-3 LDS ring (144 KB), 1 block/CU.
//   - XCD = sk&7: the 8 mt-blocks sharing a W k-window co-reside on one XCD
//     and sweep K in sync -> W re-reads become L2 hits (far W ~44 MB, was 354).
//   - R9-proven 16B-unit swizzle slot=(c+(r>>1))&3 (2 lanes/bank = free).
//   sk=32 doubles split-K atomic writes (~131 MB) -- net far-traffic still 2x lower.
// ---------------------------------------------------------------------------

typedef _Float16 f16;
typedef f16 f16x2 __attribute__((ext_vector_type(2)));
typedef f16 f16x8 __attribute__((ext_vector_type(8)));
typedef float f32x4 __attribute__((ext_vector_type(4)));

#define CHUNK   2048               // samples per pipeline pass (2 passes)
#define K_FC1   43200              // 16*270*10
#define KT32    1350               // K-tiles of 32
#define TA_F    8192               // f16 per A (mt,kt) tile: 256 rows x 32 k
#define TB_F    16384              // f16 per B (kt) tile: 512 rows x 32 k
#define BUF_F   24576              // ring buffer stride in f16 (A + B = 48 KB)

__device__ __forceinline__ float fillv(float x) { return isfinite(x) ? x : 0.0f; }

// ---------------------------------------------------------------------------
// Kernel 1: fc1_w fp32 -> f16, retiled to [kt(1350)][512][32] with 16B-unit
// swizzle: chunk c of row r stored at slot (c + (r>>1)) & 3.
// One block per kt = 1350 blocks; 2048 16B units each.
// ---------------------------------------------------------------------------
__global__ __launch_bounds__(256) void retile_w(const float* __restrict__ w,
                                                f16* __restrict__ Wt) {
    const int kt = blockIdx.x;                // 0..1349
    const int t = threadIdx.x;
    f16* dst = Wt + (size_t)kt * TB_F;
    #pragma unroll
    for (int j = 0; j < 8; ++j) {
        int q = t + 256 * j;                  // 0..2047 16B units
        int r = q >> 2, c = q & 3;            // row (0..511), k-chunk (0..3)
        const float* s = w + (size_t)r * K_FC1 + kt * 32 + c * 8;
        float4 x = *(const float4*)s;
        float4 y = *(const float4*)(s + 4);
        f16x8 o = { (f16)x.x, (f16)x.y, (f16)x.z, (f16)x.w,
                    (f16)y.x, (f16)y.y, (f16)y.z, (f16)y.w };
        int p = (c + (r >> 1)) & 3;
        *(f16x8*)(dst + r * 32 + (p << 3)) = o;
    }
}

// ---------------------------------------------------------------------------
// Kernel 2: per-sample features + folded-BN conv + relu -> A16 (scaled 2^-8),
// layout [mt(8)][kt(1350)][256][32] f16, swizzle slot=(c+(r>>1))&3.
// ---------------------------------------------------------------------------
__global__ __launch_bounds__(256) void stage_a(
    const float* __restrict__ data, const float* __restrict__ bn_g,
    const float* __restrict__ bn_b, const float* __restrict__ bn_m,
    const float* __restrict__ bn_v, const float* __restrict__ conv_w,
    const float* __restrict__ conv_b, f16* __restrict__ A16, int n0)
{
    // pool: raw window data / spread (1800 f32) during feature phases,
    // then reused as conv staging (10800 f16 = 21600 B) per 4-oc pass.
    __shared__ __align__(16) float pool[5400];
    __shared__ __align__(16) float feat[270 * 12];
    __shared__ float cwf[48];          // BN-folded conv weights (a * cw)
    __shared__ float cbf[16];          // BN-folded conv bias
    __shared__ int   pi[105], pj[105];

    float* raw = pool;
    f16*   cstage = (f16*)pool;

    const int t = threadIdx.x;
    const int n = n0 + blockIdx.x;
    const float4* src4 = (const float4*)(data + (size_t)n * 1800);
    for (int i = t; i < 450; i += 256) ((float4*)pool)[i] = src4[i];

    // BN fold (C=1): feat_bn = a*feat + bb  =>  cw' = a*cw,
    // cb' = cb + bb*(cw0+cw1+cw2)
    {
        float a  = bn_g[0] * rsqrtf(bn_v[0] + 1e-5f);
        float bb = bn_b[0] - bn_m[0] * a;
        if (t < 48) cwf[t] = conv_w[t] * a;
        if (t < 16) cbf[t] = conv_b[t] + bb * (conv_w[3 * t] + conv_w[3 * t + 1] + conv_w[3 * t + 2]);
    }
    if (t < 105) {                               // triu_indices(15, k=1) order
        int i = 0, rem = t;
        while (rem >= 14 - i) { rem -= 14 - i; ++i; }
        pi[t] = i; pj[t] = i + 1 + rem;
    }
    __syncthreads();

    // per-(f,w) stats; overwrite raw with spread (float2 access, 8B aligned)
    if (t < 180) {
        int f = t / 12, w = t % 12;
        int base = f * 120 + w * 10;
        const float2* r2 = (const float2*)(raw + base);
        float2 p0 = r2[0], p1 = r2[1], p2 = r2[2], p3 = r2[3], p4 = r2[4];
        float x[10] = { p0.x, p0.y, p1.x, p1.y, p2.x, p2.y, p3.x, p3.y, p4.x, p4.y };
        float sum = 0.f;
        #pragma unroll
        for (int s = 0; s < 10; ++s) sum += x[s];
        float mean = sum * 0.1f;
        float ret = x[9] / x[0] - 1.0f;
        float dl = 0.f;
        #pragma unroll
        for (int s = 0; s < 10; ++s) dl += x[s] * ((float)(s + 1) * (1.0f / 55.0f));
        float var = 0.f;
        float d[10];
        #pragma unroll
        for (int s = 0; s < 10; ++s) { d[s] = x[s] - mean; var += d[s] * d[s]; }
        float2* w2p = (float2*)(raw + base);
        #pragma unroll
        for (int s = 0; s < 5; ++s) w2p[s] = make_float2(d[2 * s], d[2 * s + 1]);
        var *= (1.0f / 9.0f);                    // unbiased
        float sd = sqrtf(var);
        feat[(210 + f) * 12 + w] = fillv(sd);
        feat[(225 + f) * 12 + w] = fillv(mean / sd);
        feat[(240 + f) * 12 + w] = fillv(ret);
        feat[(255 + f) * 12 + w] = fillv(dl);
    }
    __syncthreads();

    // pairwise cov / corr (float2 reads of spread)
    for (int q = t; q < 1260; q += 256) {
        int p = q / 12, w = q % 12;
        int i = pi[p], j = pj[p];
        const float2* ri = (const float2*)(raw + i * 120 + w * 10);
        const float2* rj = (const float2*)(raw + j * 120 + w * 10);
        float cv = 0.f;
        #pragma unroll
        for (int s = 0; s < 5; ++s) {
            float2 ai = ri[s], aj = rj[s];
            cv += ai.x * aj.x + ai.y * aj.y;
        }
        cv *= (1.0f / 9.0f);
        float si = feat[(210 + i) * 12 + w], sj = feat[(210 + j) * 12 + w];
        feat[p * 12 + w]         = fillv(cv / (si * sj) * 0.9f);  // *(S-1)/S
        feat[(105 + p) * 12 + w] = fillv(cv);
    }
    __syncthreads();   // raw dead from here; pool becomes cstage

    // conv(1x3) + bias + relu -> 2^-8 -> f16, 4 ocs per pass, 4 passes.
    // Pass p covers global k in [p*10800, (p+1)*10800) = 1350 16B units.
    const int s_idx = blockIdx.x;                // sample within chunk
    const int mt = s_idx >> 8, r256 = s_idx & 255;
    const int srot = (r256 >> 1) & 3;
    f16* abase = A16 + (size_t)mt * KT32 * TA_F + (size_t)r256 * 32;

    for (int p = 0; p < 4; ++p) {
        // conv compute: 1080 items = 270 h x 4 local oc
        #pragma unroll
        for (int j = 0; j < 5; ++j) {
            int item = t + (j << 8);
            if (item < 1080) {
                int h = item >> 2, ocl = item & 3, oc = (p << 2) + ocl;
                const float4* f4 = (const float4*)(feat + h * 12);
                float4 fa = f4[0], fb = f4[1], fc = f4[2];
                float fv[12] = { fa.x, fa.y, fa.z, fa.w,
                                 fb.x, fb.y, fb.z, fb.w,
                                 fc.x, fc.y, fc.z, fc.w };
                float w0 = cwf[oc * 3], w1 = cwf[oc * 3 + 1], w2 = cwf[oc * 3 + 2];
                float bz = cbf[oc];
                int kl = ocl * 2700 + h * 10;    // even -> 4B-aligned pairs
                #pragma unroll
                for (int q = 0; q < 5; ++q) {
                    float y0 = fmaf(w2, fv[2 * q + 2], fmaf(w1, fv[2 * q + 1], fmaf(w0, fv[2 * q], bz)));
                    float y1 = fmaf(w2, fv[2 * q + 3], fmaf(w1, fv[2 * q + 2], fmaf(w0, fv[2 * q + 1], bz)));
                    y0 = fminf(fmaxf(y0, 0.f) * 0.00390625f, 65000.f);
                    y1 = fminf(fmaxf(y1, 0.f) * 0.00390625f, 65000.f);
                    *(f16x2*)(cstage + kl + 2 * q) = f16x2{ (f16)y0, (f16)y1 };
                }
            }
        }
        __syncthreads();
        // store: 1350 16B units, linear LDS read -> swizzled global write
        #pragma unroll
        for (int j = 0; j < 6; ++j) {
            int u = t + (j << 8);
            if (u < 1350) {
                int U = p * 1350 + u;            // global 16B-unit index
                int kt = U >> 2, c = U & 3;      // BK=32 tile, chunk
                f16x8 ov = *(const f16x8*)(cstage + u * 8);
                *(f16x8*)(abase + (size_t)kt * TA_F + (((c + srot) & 3) << 3)) = ov;
            }
        }
        __syncthreads();                         // before next pass overwrites
    }
}

// ---------------------------------------------------------------------------
// Kernel 3: fc1 GEMM  Ysum[CHUNK,512] (+)= A * W^T (f16 MFMA)
// 256M x 512N tile, BK=32, 16 waves (1024 thr), depth-3 LDS ring (144 KB).
// Grid 256 = 8 mt x 32 sk; XCD = sk&7 so the 8 mt-blocks sharing a W window
// co-reside on one XCD (W re-reads -> L2 hits). One vmcnt + one barrier per
// K-step; prefetch depth 2 (flight ~2 steps). Atomic split-K reduce.
// ---------------------------------------------------------------------------
__global__ __launch_bounds__(1024, 1) void gemm_fc1(const f16* __restrict__ A,
                                                    const f16* __restrict__ W,
                                                    float* __restrict__ Ysum)
{
    extern __shared__ f16 lds[];   // 3 bufs x (A 8192 + B 16384) f16 = 144 KB

    const int bid = blockIdx.x;                   // 256 blocks
    const int mt = (bid >> 3) & 7;                // M-tile (256 rows)
    const int sk = (bid & 7) | (((bid >> 6) & 3) << 3);   // XCD = sk&7
    const int kt0 = sk * 42 + (sk < 6 ? sk : 6);  // uneven split: 6x43 + 26x42
    const int cnt = 42 + (sk < 6 ? 1 : 0);

    const int tid = threadIdx.x;
    const int wave = tid >> 6, lane = tid & 63;
    const int quad = lane >> 4, m16 = lane & 15;
    const int srot = (quad + (m16 >> 1)) & 3;     // swizzled slot for chunk quad
    const int wm = (wave & 3) << 6;               // 0/64/128/192
    const int wn = (wave >> 2) << 7;              // 0/128/256/384

    const f16* Ab = A + ((size_t)mt * KT32 + kt0) * TA_F;
    const f16* Bb = W + (size_t)kt0 * TB_F;

    f32x4 acc[4][8] = {};
    f16x8 a[4], b[8];

#define STAGE(BUF, KI) do {                                                    \
    const f16* ga_ = Ab + (size_t)(KI) * TA_F + tid * 8;                       \
    f16* la_ = lds + (BUF) * BUF_F + tid * 8;                                  \
    __builtin_amdgcn_global_load_lds(                                          \
        (const __attribute__((address_space(1))) void*)ga_,                    \
        (__attribute__((address_space(3))) void*)la_, 16, 0, 0);               \
    const f16* gb_ = Bb + (size_t)(KI) * TB_F + tid * 8;                       \
    f16* lb_ = lds + (BUF) * BUF_F + TA_F + tid * 8;                           \
    __builtin_amdgcn_global_load_lds(                                          \
        (const __attribute__((address_space(1))) void*)gb_,                    \
        (__attribute__((address_space(3))) void*)lb_, 16, 0, 0);               \
    __builtin_amdgcn_global_load_lds(                                          \
        (const __attribute__((address_space(1))) void*)(gb_ + 8192),           \
        (__attribute__((address_space(3))) void*)(lb_ + 8192), 16, 0, 0);      \
} while (0)

#define RD(BUF) do {                                                           \
    const f16* Ax_ = lds + (BUF) * BUF_F;                                      \
    const f16* Bx_ = lds + (BUF) * BUF_F + TA_F;                               \
    _Pragma("unroll") for (int i2_ = 0; i2_ < 4; ++i2_)                        \
        a[i2_] = *(const f16x8*)(Ax_ + (wm + i2_ * 16 + m16) * 32 + (srot << 3)); \
    _Pragma("unroll") for (int j2_ = 0; j2_ < 8; ++j2_)                        \
        b[j2_] = *(const f16x8*)(Bx_ + (wn + j2_ * 16 + m16) * 32 + (srot << 3)); \
} while (0)

#define MMA() do {                                                             \
    _Pragma("unroll") for (int i2_ = 0; i2_ < 4; ++i2_)                        \
    _Pragma("unroll") for (int j2_ = 0; j2_ < 8; ++j2_)                        \
        acc[i2_][j2_] = __builtin_amdgcn_mfma_f32_16x16x32_f16(                \
            a[i2_], b[j2_], acc[i2_][j2_], 0, 0, 0);                           \
} while (0)

    // prologue: stage steps 0 and 1 (buffers 0,1)
    STAGE(0, 0);
    STAGE(1, 1);
    asm volatile("s_waitcnt vmcnt(3)" ::: "memory");   // step-0 loads landed
    __builtin_amdgcn_s_barrier();

    int cur = 0, nx2 = 2;
    #pragma unroll 1
    for (int ti = 0; ti < cnt; ++ti) {
        if (ti + 2 < cnt) STAGE(nx2, ti + 2);          // overwrites buf read at ti-1
        RD(cur);
        __builtin_amdgcn_s_setprio(1);
        MMA();
        __builtin_amdgcn_s_setprio(0);
        if (ti + 1 < cnt) {
            if (ti + 2 < cnt)
                asm volatile("s_waitcnt vmcnt(3)" ::: "memory"); // step ti+1 landed
            else
                asm volatile("s_waitcnt vmcnt(0)" ::: "memory");
            __builtin_amdgcn_s_barrier();
        }
        cur = (cur == 2) ? 0 : cur + 1;
        nx2 = (nx2 == 2) ? 0 : nx2 + 1;
    }

#undef STAGE
#undef RD
#undef MMA

    // C/D layout: col = lane&15, row = quad*4 + reg. Atomic split-K reduce.
    float* Yb = Ysum + (size_t)(mt * 256) * 512;
    #pragma unroll
    for (int i = 0; i < 4; ++i) {
        const int row0 = wm + i * 16 + quad * 4;
        #pragma unroll
        for (int j = 0; j < 8; ++j) {
            const int col = wn + j * 16 + m16;
            #pragma unroll
            for (int r = 0; r < 4; ++r)
                unsafeAtomicAdd(&Yb[(size_t)(row0 + r) * 512 + col], acc[i][j][r]);
        }
    }
}

// ---------------------------------------------------------------------------
// Kernel 4: head = (relu(sum*256+b1)) -> fc2 + sigmoid -> fc3
// 8 samples/block, 128 threads -> 256 blocks per chunk.
// ---------------------------------------------------------------------------
__global__ __launch_bounds__(128) void head_fc23(const float* __restrict__ y1s,
                                                 const float* __restrict__ b1,
                                                 const float* __restrict__ w2,
                                                 const float* __restrict__ b2,
                                                 const float* __restrict__ w3,
                                                 const float* __restrict__ b3,
                                                 float* __restrict__ out, int n0)
{
    __shared__ float Ys[8 * 512];    // 16 KB
    __shared__ float Y2[8 * 128];    // 4 KB
    const int t = threadIdx.x;
    const float4* yb = (const float4*)(y1s + (size_t)blockIdx.x * 8 * 512);
    const float4* b1v = (const float4*)b1;
    for (int i = t; i < 8 * 128; i += 128) {
        float4 s = yb[i];
        float4 bv = b1v[i & 127];
        float4 y;
        y.x = fmaxf(fmaf(s.x, 256.f, bv.x), 0.f);
        y.y = fmaxf(fmaf(s.y, 256.f, bv.y), 0.f);
        y.z = fmaxf(fmaf(s.z, 256.f, bv.z), 0.f);
        y.w = fmaxf(fmaf(s.w, 256.f, bv.w), 0.f);
        ((float4*)Ys)[i] = y;
    }
    __syncthreads();

    float acc[8];
    float bk = b2[t];
    #pragma unroll
    for (int s = 0; s < 8; ++s) acc[s] = bk;
    const float4* wr = (const float4*)(w2 + (size_t)t * 512);
    for (int jc = 0; jc < 128; ++jc) {
        float4 w4 = wr[jc];
        #pragma unroll
        for (int s = 0; s < 8; ++s) {
            float4 y4 = *(const float4*)(Ys + s * 512 + jc * 4);
            acc[s] += w4.x * y4.x + w4.y * y4.y + w4.z * y4.z + w4.w * y4.w;
        }
    }
    #pragma unroll
    for (int s = 0; s < 8; ++s) Y2[s * 128 + t] = 1.0f / (1.0f + expf(-acc[s]));
    __syncthreads();

    if (t < 8) {
        float sm = b3[0];
        #pragma unroll 4
        for (int k = 0; k < 128; ++k) sm += Y2[t * 128 + k] * w3[k];
        out[n0 + blockIdx.x * 8 + t] = sm;
    }
}

// ---------------------------------------------------------------------------
extern "C" void kernel_launch(void* const* d_in, const int* in_sizes, int n_in,
                              void* d_out, int out_size, void* d_ws, size_t ws_size,
                              hipStream_t stream)
{
    const float* data = (const float*)d_in[0];
    const float* bn_g = (const float*)d_in[1];
    const float* bn_b = (const float*)d_in[2];
    const float* bn_m = (const float*)d_in[3];
    const float* bn_v = (const float*)d_in[4];
    const float* cw   = (const float*)d_in[5];
    const float* cb   = (const float*)d_in[6];
    const float* fc1w = (const float*)d_in[7];
    const float* fc1b = (const float*)d_in[8];
    const float* fc2w = (const float*)d_in[9];
    const float* fc2b = (const float*)d_in[10];
    const float* fc3w = (const float*)d_in[11];
    const float* fc3b = (const float*)d_in[12];
    float* out = (float*)d_out;

    // workspace layout (total ~225.6 MB, known-safe)
    const size_t A16_BYTES = (size_t)CHUNK * K_FC1 * 2;       // 176,947,200
    const size_t W16_BYTES = (size_t)512 * K_FC1 * 2;         //  44,236,800
    const size_t Y1_BYTES  = (size_t)CHUNK * 512 * 4;         //   4,194,304
    if (ws_size < A16_BYTES + W16_BYTES + Y1_BYTES) return;

    char* ws = (char*)d_ws;
    f16*   A16 = (f16*)ws;
    f16*   W16 = (f16*)(ws + A16_BYTES);
    float* y1s = (float*)(ws + A16_BYTES + W16_BYTES);

    // one-time opt-in for 144 KiB dynamic LDS (gfx950 has 160 KiB/CU)
    static int smem_set = 0;
    if (!smem_set) {
        hipFuncSetAttribute(reinterpret_cast<const void*>(gemm_fc1),
                            hipFuncAttributeMaxDynamicSharedMemorySize, 147456);
        smem_set = 1;
    }

    retile_w<<<KT32, 256, 0, stream>>>(fc1w, W16);

    for (int c = 0; c < 2; ++c) {
        int n0 = c * CHUNK;
        hipMemsetAsync(y1s, 0, Y1_BYTES, stream);
        stage_a<<<CHUNK, 256, 0, stream>>>(data, bn_g, bn_b, bn_m, bn_v, cw, cb, A16, n0);
        gemm_fc1<<<256, 1024, 147456, stream>>>(A16, W16, y1s);
        head_fc23<<<CHUNK / 8, 128, 0, stream>>>(y1s, fc1b, fc2w, fc2b, fc3w, fc3b, out, n0);
    }
}

// Round 5
// 533.228 us; speedup vs baseline: 3.8819x; 3.8819x over previous
//
#include <hip/hip_runtime.h>
#include <cstdint>
#include <cstddef>

// ---------------------------------------------------------------------------
// AlphaNet: features -> BN -> conv(1x3,16) -> relu -> fc1(43200->512) -> relu
//          -> fc2(512->128) -> sigmoid -> fc3(128->1)
// R14: recovery + one isolated change. R13's 256x512 tile spilled acc to
//   scratch (VGPR budget 128 @ 16 waves; acc alone needs 128) -> 4 GB spill
//   traffic. Restored the best-measured R10/R11 build (gemm 127 us, 4-phase
//   256x256, counted vmcnt(4)). ONLY change: bid remap mt=bid>>5/slot=bid&31
//   so the 8 mt-blocks sharing one W K-window (1.38 MB < 4 MB XCD-L2) land on
//   the SAME XCD -> W re-stagings become L2 hits. FETCH_SIZE is the probe.
// ---------------------------------------------------------------------------

typedef _Float16 f16;
typedef f16 f16x2 __attribute__((ext_vector_type(2)));
typedef f16 f16x8 __attribute__((ext_vector_type(8)));
typedef float f32x4 __attribute__((ext_vector_type(4)));

#define CHUNK   2048               // samples per pipeline pass (2 passes)
#define K_FC1   43200              // 16*270*10
#define KT_TOT  675                // K-tiles of 64
#define TILE_F  16384              // f16 per (tile,kt): 256 rows x 64 k
#define HALF_F  8192               // f16 per half-tile: 128 rows x 64 k

__device__ __forceinline__ float fillv(float x) { return isfinite(x) ? x : 0.0f; }

// ---------------------------------------------------------------------------
// Kernel 1: fc1_w fp32 -> f16, retiled to [nt(2)][kt(675)][half(2)][128][64]
// with 16B-chunk swizzle: logical chunk c of row r stored at slot c ^ (r&7).
// One block per (nt,kt) = 1350 blocks; 2048 16B units each.
// ---------------------------------------------------------------------------
__global__ __launch_bounds__(256) void retile_w(const float* __restrict__ w,
                                                f16* __restrict__ Wt) {
    const int bid = blockIdx.x;               // nt*675 + kt
    const int nt = bid / KT_TOT, kt = bid % KT_TOT;
    const int t = threadIdx.x;
    f16* dst = Wt + (size_t)bid * TILE_F;
    #pragma unroll
    for (int j = 0; j < 8; ++j) {
        int q = t + 256 * j;                  // 0..2047 16B units
        int half = q >> 10, rr = (q >> 3) & 127, c = q & 7;
        const float* s = w + (size_t)(nt * 256 + half * 128 + rr) * K_FC1 + kt * 64 + c * 8;
        float4 x = *(const float4*)s;
        float4 y = *(const float4*)(s + 4);
        f16x8 o = { (f16)x.x, (f16)x.y, (f16)x.z, (f16)x.w,
                    (f16)y.x, (f16)y.y, (f16)y.z, (f16)y.w };
        int p = c ^ (rr & 7);
        *(f16x8*)(dst + (size_t)half * HALF_F + rr * 64 + p * 8) = o;
    }
}

// ---------------------------------------------------------------------------
// Kernel 2: per-sample features + folded-BN conv + relu -> A16 (scaled 2^-8),
// layout [mt(8)][kt(675)][half(2)][128][64] f16, chunk swizzle c ^ (row&7).
// Conv phase: item = (h, oc); feat row in regs; outputs staged in LDS (f16),
// then linear readback -> swizzled 16B-unit global stores.
// ---------------------------------------------------------------------------
__global__ __launch_bounds__(256) void stage_a(
    const float* __restrict__ data, const float* __restrict__ bn_g,
    const float* __restrict__ bn_b, const float* __restrict__ bn_m,
    const float* __restrict__ bn_v, const float* __restrict__ conv_w,
    const float* __restrict__ conv_b, f16* __restrict__ A16, int n0)
{
    // pool: raw window data / spread (1800 f32) during feature phases,
    // then reused as conv staging (10800 f16 = 21600 B) per 4-oc pass.
    __shared__ __align__(16) float pool[5400];
    __shared__ __align__(16) float feat[270 * 12];
    __shared__ float cwf[48];          // BN-folded conv weights (a * cw)
    __shared__ float cbf[16];          // BN-folded conv bias
    __shared__ int   pi[105], pj[105];

    float* raw = pool;
    f16*   cstage = (f16*)pool;

    const int t = threadIdx.x;
    const int n = n0 + blockIdx.x;
    const float4* src4 = (const float4*)(data + (size_t)n * 1800);
    for (int i = t; i < 450; i += 256) ((float4*)pool)[i] = src4[i];

    // BN fold (C=1): feat_bn = a*feat + bb  =>  cw' = a*cw,
    // cb' = cb + bb*(cw0+cw1+cw2)
    {
        float a  = bn_g[0] * rsqrtf(bn_v[0] + 1e-5f);
        float bb = bn_b[0] - bn_m[0] * a;
        if (t < 48) cwf[t] = conv_w[t] * a;
        if (t < 16) cbf[t] = conv_b[t] + bb * (conv_w[3 * t] + conv_w[3 * t + 1] + conv_w[3 * t + 2]);
    }
    if (t < 105) {                               // triu_indices(15, k=1) order
        int i = 0, rem = t;
        while (rem >= 14 - i) { rem -= 14 - i; ++i; }
        pi[t] = i; pj[t] = i + 1 + rem;
    }
    __syncthreads();

    // per-(f,w) stats; overwrite raw with spread (float2 access, 8B aligned)
    if (t < 180) {
        int f = t / 12, w = t % 12;
        int base = f * 120 + w * 10;
        const float2* r2 = (const float2*)(raw + base);
        float2 p0 = r2[0], p1 = r2[1], p2 = r2[2], p3 = r2[3], p4 = r2[4];
        float x[10] = { p0.x, p0.y, p1.x, p1.y, p2.x, p2.y, p3.x, p3.y, p4.x, p4.y };
        float sum = 0.f;
        #pragma unroll
        for (int s = 0; s < 10; ++s) sum += x[s];
        float mean = sum * 0.1f;
        float ret = x[9] / x[0] - 1.0f;
        float dl = 0.f;
        #pragma unroll
        for (int s = 0; s < 10; ++s) dl += x[s] * ((float)(s + 1) * (1.0f / 55.0f));
        float var = 0.f;
        float d[10];
        #pragma unroll
        for (int s = 0; s < 10; ++s) { d[s] = x[s] - mean; var += d[s] * d[s]; }
        float2* w2p = (float2*)(raw + base);
        #pragma unroll
        for (int s = 0; s < 5; ++s) w2p[s] = make_float2(d[2 * s], d[2 * s + 1]);
        var *= (1.0f / 9.0f);                    // unbiased
        float sd = sqrtf(var);
        feat[(210 + f) * 12 + w] = fillv(sd);
        feat[(225 + f) * 12 + w] = fillv(mean / sd);
        feat[(240 + f) * 12 + w] = fillv(ret);
        feat[(255 + f) * 12 + w] = fillv(dl);
    }
    __syncthreads();

    // pairwise cov / corr (float2 reads of spread)
    for (int q = t; q < 1260; q += 256) {
        int p = q / 12, w = q % 12;
        int i = pi[p], j = pj[p];
        const float2* ri = (const float2*)(raw + i * 120 + w * 10);
        const float2* rj = (const float2*)(raw + j * 120 + w * 10);
        float cv = 0.f;
        #pragma unroll
        for (int s = 0; s < 5; ++s) {
            float2 ai = ri[s], aj = rj[s];
            cv += ai.x * aj.x + ai.y * aj.y;
        }
        cv *= (1.0f / 9.0f);
        float si = feat[(210 + i) * 12 + w], sj = feat[(210 + j) * 12 + w];
        feat[p * 12 + w]         = fillv(cv / (si * sj) * 0.9f);  // *(S-1)/S
        feat[(105 + p) * 12 + w] = fillv(cv);
    }
    __syncthreads();   // raw dead from here; pool becomes cstage

    // conv(1x3) + bias + relu -> 2^-8 -> f16, 4 ocs per pass, 4 passes.
    // Pass p covers global k in [p*10800, (p+1)*10800) = 1350 16B units.
    const int s_idx = blockIdx.x;                // sample within chunk
    const int mt = s_idx >> 8, r256 = s_idx & 255;
    const int half = r256 >> 7, rloc = r256 & 127, rsw = r256 & 7;
    f16* abase = A16 + ((size_t)(mt * KT_TOT) * 2 + half) * HALF_F + (size_t)rloc * 64;

    for (int p = 0; p < 4; ++p) {
        // conv compute: 1080 items = 270 h x 4 local oc
        #pragma unroll
        for (int j = 0; j < 5; ++j) {
            int item = t + (j << 8);
            if (item < 1080) {
                int h = item >> 2, ocl = item & 3, oc = (p << 2) + ocl;
                const float4* f4 = (const float4*)(feat + h * 12);
                float4 fa = f4[0], fb = f4[1], fc = f4[2];
                float fv[12] = { fa.x, fa.y, fa.z, fa.w,
                                 fb.x, fb.y, fb.z, fb.w,
                                 fc.x, fc.y, fc.z, fc.w };
                float w0 = cwf[oc * 3], w1 = cwf[oc * 3 + 1], w2 = cwf[oc * 3 + 2];
                float bz = cbf[oc];
                int kl = ocl * 2700 + h * 10;    // even -> 4B-aligned pairs
                #pragma unroll
                for (int q = 0; q < 5; ++q) {
                    float y0 = fmaf(w2, fv[2 * q + 2], fmaf(w1, fv[2 * q + 1], fmaf(w0, fv[2 * q], bz)));
                    float y1 = fmaf(w2, fv[2 * q + 3], fmaf(w1, fv[2 * q + 2], fmaf(w0, fv[2 * q + 1], bz)));
                    y0 = fminf(fmaxf(y0, 0.f) * 0.00390625f, 65000.f);
                    y1 = fminf(fmaxf(y1, 0.f) * 0.00390625f, 65000.f);
                    *(f16x2*)(cstage + kl + 2 * q) = f16x2{ (f16)y0, (f16)y1 };
                }
            }
        }
        __syncthreads();
        // store: 1350 16B units, linear LDS read -> swizzled global write
        #pragma unroll
        for (int j = 0; j < 6; ++j) {
            int u = t + (j << 8);
            if (u < 1350) {
                int U = p * 1350 + u;            // global 16B-unit index
                int kt = U >> 3, c = U & 7;
                f16x8 ov = *(const f16x8*)(cstage + u * 8);
                *(f16x8*)(abase + (size_t)kt * TILE_F + ((c ^ rsw) << 3)) = ov;
            }
        }
        __syncthreads();                         // before next pass overwrites
    }
}

// ---------------------------------------------------------------------------
// Kernel 3: fc1 GEMM  Ysum[CHUNK,512] (+)= A * W^T (f16 MFMA)
// 4-phase schedule: 256x256 tile, BK=64, 8 waves (512 thr), per-wave 128x64
// split as 64-row/32-col slices over BOTH tile halves.
// 4 phases per K-tile; counted vmcnt(4); setprio around MFMA clusters.
// LDS 128 KiB dynamic (2 dbuf x (A 32K + B 32K)) -> 1 block/CU, grid 256.
// R14 remap: mt = bid>>5, slot = bid&31 -> XCD (= bid&7) groups the 8
// mt-blocks sharing one W K-window; W slice (1.38 MB) stays L2-resident.
// ---------------------------------------------------------------------------
__global__ __launch_bounds__(512, 2) void gemm_fc1(const f16* __restrict__ A,
                                                   const f16* __restrict__ W,
                                                   float* __restrict__ Ysum)
{
    extern __shared__ f16 lds[];   // [0,32768): A bufs; [32768,65536): B bufs

    const int bid = blockIdx.x;                   // 256 blocks
    const int mt = bid >> 5;                      // 0..7  M-tile
    const int slot = bid & 31;                    // (nt,sk) -> XCD = slot&7
    const int nt = slot & 1;
    const int sk = slot >> 1;                     // 0..15
    const int kt0 = sk * 42 + (sk < 3 ? sk : 3);  // uneven split: 3x43 + 13x42
    const int cnt = 42 + (sk < 3 ? 1 : 0);

    const int tid = threadIdx.x;
    const int wave = tid >> 6, lane = tid & 63;
    const int quad = lane >> 4, m16 = lane & 15;
    const int rsw = m16 & 7;                      // row&7 == m16&7 (bases = 0 mod 8)
    const int wm = (wave & 1) << 6;               // 0 / 64   (row slice in each half)
    const int wn = (wave >> 1) << 5;              // 0/32/64/96 (col slice in each half)

    const f16* Ab = A + (size_t)(mt * KT_TOT + kt0) * TILE_F;
    const f16* Bb = W + (size_t)(nt * KT_TOT + kt0) * TILE_F;

    f32x4 acc[8][4] = {};
    f16x8 a[4][2], bA[2][2], bB[2][2];

#define STAGE_A(BUF, HALF, KI) do {                                            \
    const f16* g_ = Ab + (size_t)(KI) * TILE_F + (HALF) * HALF_F + tid * 8;    \
    f16* l_ = lds + (BUF) * TILE_F + (HALF) * HALF_F + tid * 8;                \
    __builtin_amdgcn_global_load_lds(                                          \
        (const __attribute__((address_space(1))) void*)g_,                     \
        (__attribute__((address_space(3))) void*)l_, 16, 0, 0);                \
    __builtin_amdgcn_global_load_lds(                                          \
        (const __attribute__((address_space(1))) void*)(g_ + 4096),            \
        (__attribute__((address_space(3))) void*)(l_ + 4096), 16, 0, 0);       \
} while (0)

#define STAGE_B(BUF, HALF, KI) do {                                            \
    const f16* g_ = Bb + (size_t)(KI) * TILE_F + (HALF) * HALF_F + tid * 8;    \
    f16* l_ = lds + 32768 + (BUF) * TILE_F + (HALF) * HALF_F + tid * 8;        \
    __builtin_amdgcn_global_load_lds(                                          \
        (const __attribute__((address_space(1))) void*)g_,                     \
        (__attribute__((address_space(3))) void*)l_, 16, 0, 0);                \
    __builtin_amdgcn_global_load_lds(                                          \
        (const __attribute__((address_space(1))) void*)(g_ + 4096),            \
        (__attribute__((address_space(3))) void*)(l_ + 4096), 16, 0, 0);       \
} while (0)

#define RD_A(MH, BUF) do {                                                     \
    _Pragma("unroll") for (int i2_ = 0; i2_ < 4; ++i2_)                        \
    _Pragma("unroll") for (int kh_ = 0; kh_ < 2; ++kh_)                        \
        a[i2_][kh_] = *(const f16x8*)(lds + (BUF) * TILE_F + (MH) * HALF_F     \
            + (wm + i2_ * 16 + m16) * 64 + (((kh_ * 4 + quad) ^ rsw) << 3));   \
} while (0)

#define RD_B(DST, NH, BUF) do {                                                \
    _Pragma("unroll") for (int j2_ = 0; j2_ < 2; ++j2_)                        \
    _Pragma("unroll") for (int kh_ = 0; kh_ < 2; ++kh_)                        \
        DST[j2_][kh_] = *(const f16x8*)(lds + 32768 + (BUF) * TILE_F           \
            + (NH) * HALF_F                                                    \
            + (wn + j2_ * 16 + m16) * 64 + (((kh_ * 4 + quad) ^ rsw) << 3));   \
} while (0)

#define MMA(IO, JO, BF) do {                                                   \
    _Pragma("unroll") for (int i2_ = 0; i2_ < 4; ++i2_)                        \
    _Pragma("unroll") for (int j2_ = 0; j2_ < 2; ++j2_)                        \
    _Pragma("unroll") for (int kh_ = 0; kh_ < 2; ++kh_)                        \
        acc[(IO) + i2_][(JO) + j2_] = __builtin_amdgcn_mfma_f32_16x16x32_f16(  \
            a[i2_][kh_], BF[j2_][kh_], acc[(IO) + i2_][(JO) + j2_], 0, 0, 0);  \
} while (0)

    // prologue: stage tile 0 into buf 0 (order h0=A0, h1=B0, h2=B1, h3=A1)
    STAGE_A(0, 0, 0);
    STAGE_B(0, 0, 0);
    STAGE_B(0, 1, 0);
    STAGE_A(0, 1, 0);
    asm volatile("s_waitcnt vmcnt(4)" ::: "memory");  // h0,h1 landed
    __builtin_amdgcn_s_barrier();

    #pragma unroll 1
    for (int ti = 0; ti < cnt - 1; ++ti) {
        const int bc = ti & 1, bn = bc ^ 1;
        // ---- P1: quad(Mhalf0, Nhalf0); prefetch next A-half0 (h0')
        RD_A(0, bc); RD_B(bA, 0, bc);
        STAGE_A(bn, 0, ti + 1);
        __builtin_amdgcn_s_barrier();
        __builtin_amdgcn_s_setprio(1);
        MMA(0, 0, bA);
        __builtin_amdgcn_s_setprio(0);
        asm volatile("s_waitcnt vmcnt(4)" ::: "memory");  // h2 (B1) landed
        __builtin_amdgcn_s_barrier();
        // ---- P2: quad(0,1); prefetch next B-half0 (h1')
        RD_B(bB, 1, bc);
        STAGE_B(bn, 0, ti + 1);
        __builtin_amdgcn_s_barrier();
        __builtin_amdgcn_s_setprio(1);
        MMA(0, 2, bB);
        __builtin_amdgcn_s_setprio(0);
        asm volatile("s_waitcnt vmcnt(4)" ::: "memory");  // h3 (A1) landed
        __builtin_amdgcn_s_barrier();
        // ---- P3: quad(1,1); prefetch next B-half1 (h2')
        RD_A(1, bc);
        STAGE_B(bn, 1, ti + 1);
        __builtin_amdgcn_s_barrier();
        __builtin_amdgcn_s_setprio(1);
        MMA(4, 2, bB);
        __builtin_amdgcn_s_setprio(0);
        __builtin_amdgcn_s_barrier();
        // ---- P4: quad(1,0) from regs; prefetch next A-half1 (h3')
        STAGE_A(bn, 1, ti + 1);
        __builtin_amdgcn_s_barrier();
        __builtin_amdgcn_s_setprio(1);
        MMA(4, 0, bA);
        __builtin_amdgcn_s_setprio(0);
        asm volatile("s_waitcnt vmcnt(4)" ::: "memory");  // h0',h1' landed
        __builtin_amdgcn_s_barrier();
    }

    // epilogue tile (no prefetch; drains vmcnt once)
    {
        const int bc = (cnt - 1) & 1;
        RD_A(0, bc); RD_B(bA, 0, bc);
        __builtin_amdgcn_s_setprio(1);
        MMA(0, 0, bA);
        __builtin_amdgcn_s_setprio(0);
        asm volatile("s_waitcnt vmcnt(2)" ::: "memory");  // h2 landed
        __builtin_amdgcn_s_barrier();
        RD_B(bB, 1, bc);
        __builtin_amdgcn_s_setprio(1);
        MMA(0, 2, bB);
        __builtin_amdgcn_s_setprio(0);
        asm volatile("s_waitcnt vmcnt(0)" ::: "memory");  // h3 landed
        __builtin_amdgcn_s_barrier();
        RD_A(1, bc);
        __builtin_amdgcn_s_setprio(1);
        MMA(4, 2, bB);
        MMA(4, 0, bA);
        __builtin_amdgcn_s_setprio(0);
    }

#undef STAGE_A
#undef STAGE_B
#undef RD_A
#undef RD_B
#undef MMA

    // C/D layout: col = lane&15, row = quad*4 + reg. Atomic split-K reduce.
    // acc[i][j]: row half = i>>2, row frag = i&3; col half = j>>1, frag = j&1.
    float* Yb = Ysum + (size_t)(mt * 256) * 512 + nt * 256;
    #pragma unroll
    for (int i = 0; i < 8; ++i) {
        const int row0 = (i >> 2) * 128 + wm + (i & 3) * 16 + quad * 4;
        #pragma unroll
        for (int j = 0; j < 4; ++j) {
            const int col = (j >> 1) * 128 + wn + (j & 1) * 16 + m16;
            #pragma unroll
            for (int r = 0; r < 4; ++r)
                unsafeAtomicAdd(&Yb[(size_t)(row0 + r) * 512 + col], acc[i][j][r]);
        }
    }
}

// ---------------------------------------------------------------------------
// Kernel 4: head = (relu(sum*256+b1)) -> fc2 + sigmoid -> fc3
// 8 samples/block, 128 threads -> 256 blocks per chunk.
// ---------------------------------------------------------------------------
__global__ __launch_bounds__(128) void head_fc23(const float* __restrict__ y1s,
                                                 const float* __restrict__ b1,
                                                 const float* __restrict__ w2,
                                                 const float* __restrict__ b2,
                                                 const float* __restrict__ w3,
                                                 const float* __restrict__ b3,
                                                 float* __restrict__ out, int n0)
{
    __shared__ float Ys[8 * 512];    // 16 KB
    __shared__ float Y2[8 * 128];    // 4 KB
    const int t = threadIdx.x;
    const float4* yb = (const float4*)(y1s + (size_t)blockIdx.x * 8 * 512);
    const float4* b1v = (const float4*)b1;
    for (int i = t; i < 8 * 128; i += 128) {
        float4 s = yb[i];
        float4 bv = b1v[i & 127];
        float4 y;
        y.x = fmaxf(fmaf(s.x, 256.f, bv.x), 0.f);
        y.y = fmaxf(fmaf(s.y, 256.f, bv.y), 0.f);
        y.z = fmaxf(fmaf(s.z, 256.f, bv.z), 0.f);
        y.w = fmaxf(fmaf(s.w, 256.f, bv.w), 0.f);
        ((float4*)Ys)[i] = y;
    }
    __syncthreads();

    float acc[8];
    float bk = b2[t];
    #pragma unroll
    for (int s = 0; s < 8; ++s) acc[s] = bk;
    const float4* wr = (const float4*)(w2 + (size_t)t * 512);
    for (int jc = 0; jc < 128; ++jc) {
        float4 w4 = wr[jc];
        #pragma unroll
        for (int s = 0; s < 8; ++s) {
            float4 y4 = *(const float4*)(Ys + s * 512 + jc * 4);
            acc[s] += w4.x * y4.x + w4.y * y4.y + w4.z * y4.z + w4.w * y4.w;
        }
    }
    #pragma unroll
    for (int s = 0; s < 8; ++s) Y2[s * 128 + t] = 1.0f / (1.0f + expf(-acc[s]));
    __syncthreads();

    if (t < 8) {
        float sm = b3[0];
        #pragma unroll 4
        for (int k = 0; k < 128; ++k) sm += Y2[t * 128 + k] * w3[k];
        out[n0 + blockIdx.x * 8 + t] = sm;
    }
}

// ---------------------------------------------------------------------------
extern "C" void kernel_launch(void* const* d_in, const int* in_sizes, int n_in,
                              void* d_out, int out_size, void* d_ws, size_t ws_size,
                              hipStream_t stream)
{
    const float* data = (const float*)d_in[0];
    const float* bn_g = (const float*)d_in[1];
    const float* bn_b = (const float*)d_in[2];
    const float* bn_m = (const float*)d_in[3];
    const float* bn_v = (const float*)d_in[4];
    const float* cw   = (const float*)d_in[5];
    const float* cb   = (const float*)d_in[6];
    const float* fc1w = (const float*)d_in[7];
    const float* fc1b = (const float*)d_in[8];
    const float* fc2w = (const float*)d_in[9];
    const float* fc2b = (const float*)d_in[10];
    const float* fc3w = (const float*)d_in[11];
    const float* fc3b = (const float*)d_in[12];
    float* out = (float*)d_out;

    // workspace layout (total ~225.6 MB, known-safe)
    const size_t A16_BYTES = (size_t)CHUNK * K_FC1 * 2;       // 176,947,200
    const size_t W16_BYTES = (size_t)512 * K_FC1 * 2;         //  44,236,800
    const size_t Y1_BYTES  = (size_t)CHUNK * 512 * 4;         //   4,194,304
    if (ws_size < A16_BYTES + W16_BYTES + Y1_BYTES) return;

    char* ws = (char*)d_ws;
    f16*   A16 = (f16*)ws;
    f16*   W16 = (f16*)(ws + A16_BYTES);
    float* y1s = (float*)(ws + A16_BYTES + W16_BYTES);

    // one-time opt-in for 128 KiB dynamic LDS (gfx950 has 160 KiB/CU)
    static int smem_set = 0;
    if (!smem_set) {
        hipFuncSetAttribute(reinterpret_cast<const void*>(gemm_fc1),
                            hipFuncAttributeMaxDynamicSharedMemorySize, 131072);
        smem_set = 1;
    }

    retile_w<<<2 * KT_TOT, 256, 0, stream>>>(fc1w, W16);

    for (int c = 0; c < 2; ++c) {
        int n0 = c * CHUNK;
        hipMemsetAsync(y1s, 0, Y1_BYTES, stream);
        stage_a<<<CHUNK, 256, 0, stream>>>(data, bn_g, bn_b, bn_m, bn_v, cw, cb, A16, n0);
        gemm_fc1<<<256, 512, 131072, stream>>>(A16, W16, y1s);
        head_fc23<<<CHUNK / 8, 128, 0, stream>>>(y1s, fc1b, fc2w, fc2b, fc3w, fc3b, out, n0);
    }
}

// Round 6
// 524.855 us; speedup vs baseline: 3.9438x; 1.0160x over previous
//
#include <hip/hip_runtime.h>
#include <cstdint>
#include <cstddef>

// ---------------------------------------------------------------------------
// AlphaNet: features -> BN -> conv(1x3,16) -> relu -> fc1(43200->512) -> relu
//          -> fc2(512->128) -> sigmoid -> fc3(128->1)
// R15: A16 de-tiled to plain row-major [2048][43200] f16.
//   - stage_a store phase: contiguous streaming stores (was 128-B scatter at
//     32-KB stride -> suspected ~20-40us/launch HBM-write tax).
//   - gemm STAGE_A: per-lane swizzled global SOURCE (lane reads
//     A[row][kt*64 + ((chunk ^ (row&7))<<3)]), linear LDS dest -> LDS image
//     byte-identical to R14; RD_A/MMA/epilogue untouched.
//   W16 tiled path, 4-phase schedule, XCD W-grouping (R14, FETCH -65MB): kept.
// ---------------------------------------------------------------------------

typedef _Float16 f16;
typedef f16 f16x2 __attribute__((ext_vector_type(2)));
typedef f16 f16x8 __attribute__((ext_vector_type(8)));
typedef float f32x4 __attribute__((ext_vector_type(4)));

#define CHUNK   2048               // samples per pipeline pass (2 passes)
#define K_FC1   43200              // 16*270*10
#define KT_TOT  675                // K-tiles of 64
#define TILE_F  16384              // f16 per W (nt,kt) tile: 256 rows x 64 k
#define HALF_F  8192               // f16 per half-tile: 128 rows x 64 k

__device__ __forceinline__ float fillv(float x) { return isfinite(x) ? x : 0.0f; }

// ---------------------------------------------------------------------------
// Kernel 1: fc1_w fp32 -> f16, retiled to [nt(2)][kt(675)][half(2)][128][64]
// with 16B-chunk swizzle: logical chunk c of row r stored at slot c ^ (r&7).
// One block per (nt,kt) = 1350 blocks; 2048 16B units each.
// ---------------------------------------------------------------------------
__global__ __launch_bounds__(256) void retile_w(const float* __restrict__ w,
                                                f16* __restrict__ Wt) {
    const int bid = blockIdx.x;               // nt*675 + kt
    const int nt = bid / KT_TOT, kt = bid % KT_TOT;
    const int t = threadIdx.x;
    f16* dst = Wt + (size_t)bid * TILE_F;
    #pragma unroll
    for (int j = 0; j < 8; ++j) {
        int q = t + 256 * j;                  // 0..2047 16B units
        int half = q >> 10, rr = (q >> 3) & 127, c = q & 7;
        const float* s = w + (size_t)(nt * 256 + half * 128 + rr) * K_FC1 + kt * 64 + c * 8;
        float4 x = *(const float4*)s;
        float4 y = *(const float4*)(s + 4);
        f16x8 o = { (f16)x.x, (f16)x.y, (f16)x.z, (f16)x.w,
                    (f16)y.x, (f16)y.y, (f16)y.z, (f16)y.w };
        int p = c ^ (rr & 7);
        *(f16x8*)(dst + (size_t)half * HALF_F + rr * 64 + p * 8) = o;
    }
}

// ---------------------------------------------------------------------------
// Kernel 2: per-sample features + folded-BN conv + relu -> A16 (scaled 2^-8),
// plain row-major [sample][43200] f16 -> store phase is pure streaming.
// ---------------------------------------------------------------------------
__global__ __launch_bounds__(256) void stage_a(
    const float* __restrict__ data, const float* __restrict__ bn_g,
    const float* __restrict__ bn_b, const float* __restrict__ bn_m,
    const float* __restrict__ bn_v, const float* __restrict__ conv_w,
    const float* __restrict__ conv_b, f16* __restrict__ A16, int n0)
{
    // pool: raw window data / spread (1800 f32) during feature phases,
    // then reused as conv staging (10800 f16 = 21600 B) per 4-oc pass.
    __shared__ __align__(16) float pool[5400];
    __shared__ __align__(16) float feat[270 * 12];
    __shared__ float cwf[48];          // BN-folded conv weights (a * cw)
    __shared__ float cbf[16];          // BN-folded conv bias
    __shared__ int   pi[105], pj[105];

    float* raw = pool;
    f16*   cstage = (f16*)pool;

    const int t = threadIdx.x;
    const int n = n0 + blockIdx.x;
    const float4* src4 = (const float4*)(data + (size_t)n * 1800);
    for (int i = t; i < 450; i += 256) ((float4*)pool)[i] = src4[i];

    // BN fold (C=1): feat_bn = a*feat + bb  =>  cw' = a*cw,
    // cb' = cb + bb*(cw0+cw1+cw2)
    {
        float a  = bn_g[0] * rsqrtf(bn_v[0] + 1e-5f);
        float bb = bn_b[0] - bn_m[0] * a;
        if (t < 48) cwf[t] = conv_w[t] * a;
        if (t < 16) cbf[t] = conv_b[t] + bb * (conv_w[3 * t] + conv_w[3 * t + 1] + conv_w[3 * t + 2]);
    }
    if (t < 105) {                               // triu_indices(15, k=1) order
        int i = 0, rem = t;
        while (rem >= 14 - i) { rem -= 14 - i; ++i; }
        pi[t] = i; pj[t] = i + 1 + rem;
    }
    __syncthreads();

    // per-(f,w) stats; overwrite raw with spread (float2 access, 8B aligned)
    if (t < 180) {
        int f = t / 12, w = t % 12;
        int base = f * 120 + w * 10;
        const float2* r2 = (const float2*)(raw + base);
        float2 p0 = r2[0], p1 = r2[1], p2 = r2[2], p3 = r2[3], p4 = r2[4];
        float x[10] = { p0.x, p0.y, p1.x, p1.y, p2.x, p2.y, p3.x, p3.y, p4.x, p4.y };
        float sum = 0.f;
        #pragma unroll
        for (int s = 0; s < 10; ++s) sum += x[s];
        float mean = sum * 0.1f;
        float ret = x[9] / x[0] - 1.0f;
        float dl = 0.f;
        #pragma unroll
        for (int s = 0; s < 10; ++s) dl += x[s] * ((float)(s + 1) * (1.0f / 55.0f));
        float var = 0.f;
        float d[10];
        #pragma unroll
        for (int s = 0; s < 10; ++s) { d[s] = x[s] - mean; var += d[s] * d[s]; }
        float2* w2p = (float2*)(raw + base);
        #pragma unroll
        for (int s = 0; s < 5; ++s) w2p[s] = make_float2(d[2 * s], d[2 * s + 1]);
        var *= (1.0f / 9.0f);                    // unbiased
        float sd = sqrtf(var);
        feat[(210 + f) * 12 + w] = fillv(sd);
        feat[(225 + f) * 12 + w] = fillv(mean / sd);
        feat[(240 + f) * 12 + w] = fillv(ret);
        feat[(255 + f) * 12 + w] = fillv(dl);
    }
    __syncthreads();

    // pairwise cov / corr (float2 reads of spread)
    for (int q = t; q < 1260; q += 256) {
        int p = q / 12, w = q % 12;
        int i = pi[p], j = pj[p];
        const float2* ri = (const float2*)(raw + i * 120 + w * 10);
        const float2* rj = (const float2*)(raw + j * 120 + w * 10);
        float cv = 0.f;
        #pragma unroll
        for (int s = 0; s < 5; ++s) {
            float2 ai = ri[s], aj = rj[s];
            cv += ai.x * aj.x + ai.y * aj.y;
        }
        cv *= (1.0f / 9.0f);
        float si = feat[(210 + i) * 12 + w], sj = feat[(210 + j) * 12 + w];
        feat[p * 12 + w]         = fillv(cv / (si * sj) * 0.9f);  // *(S-1)/S
        feat[(105 + p) * 12 + w] = fillv(cv);
    }
    __syncthreads();   // raw dead from here; pool becomes cstage

    // conv(1x3) + bias + relu -> 2^-8 -> f16, 4 ocs per pass, 4 passes.
    // Pass p covers global k in [p*10800, (p+1)*10800).
    f16* abase = A16 + (size_t)blockIdx.x * K_FC1;

    for (int p = 0; p < 4; ++p) {
        // conv compute: 1080 items = 270 h x 4 local oc
        #pragma unroll
        for (int j = 0; j < 5; ++j) {
            int item = t + (j << 8);
            if (item < 1080) {
                int h = item >> 2, ocl = item & 3, oc = (p << 2) + ocl;
                const float4* f4 = (const float4*)(feat + h * 12);
                float4 fa = f4[0], fb = f4[1], fc = f4[2];
                float fv[12] = { fa.x, fa.y, fa.z, fa.w,
                                 fb.x, fb.y, fb.z, fb.w,
                                 fc.x, fc.y, fc.z, fc.w };
                float w0 = cwf[oc * 3], w1 = cwf[oc * 3 + 1], w2 = cwf[oc * 3 + 2];
                float bz = cbf[oc];
                int kl = ocl * 2700 + h * 10;    // even -> 4B-aligned pairs
                #pragma unroll
                for (int q = 0; q < 5; ++q) {
                    float y0 = fmaf(w2, fv[2 * q + 2], fmaf(w1, fv[2 * q + 1], fmaf(w0, fv[2 * q], bz)));
                    float y1 = fmaf(w2, fv[2 * q + 3], fmaf(w1, fv[2 * q + 2], fmaf(w0, fv[2 * q + 1], bz)));
                    y0 = fminf(fmaxf(y0, 0.f) * 0.00390625f, 65000.f);
                    y1 = fminf(fmaxf(y1, 0.f) * 0.00390625f, 65000.f);
                    *(f16x2*)(cstage + kl + 2 * q) = f16x2{ (f16)y0, (f16)y1 };
                }
            }
        }
        __syncthreads();
        // store: 1350 16B units, linear LDS read -> CONTIGUOUS global write
        #pragma unroll
        for (int j = 0; j < 6; ++j) {
            int u = t + (j << 8);
            if (u < 1350) {
                f16x8 ov = *(const f16x8*)(cstage + u * 8);
                *(f16x8*)(abase + (size_t)(p * 1350 + u) * 8) = ov;
            }
        }
        __syncthreads();                         // before next pass overwrites
    }
}

// ---------------------------------------------------------------------------
// Kernel 3: fc1 GEMM  Ysum[CHUNK,512] (+)= A * W^T (f16 MFMA)
// 4-phase schedule: 256x256 tile, BK=64, 8 waves (512 thr); counted vmcnt(4);
// setprio around MFMA clusters; LDS 128 KiB dynamic -> 1 block/CU, grid 256.
// R14 remap kept: mt = bid>>5 -> XCD (= bid&7) groups the 8 mt-blocks sharing
// one W K-window (W slice L2-resident; FETCH -65 MB verified).
// R15: A is row-major; STAGE_A reads per-lane pre-swizzled source addresses
// (lane row=tid>>3, chunk=tid&7 reads A[row][kt*64 + ((chunk^(row&7))<<3)]) ->
// LDS image identical to the old tiled layout; RD_A unchanged.
// ---------------------------------------------------------------------------
__global__ __launch_bounds__(512, 2) void gemm_fc1(const f16* __restrict__ A,
                                                   const f16* __restrict__ W,
                                                   float* __restrict__ Ysum)
{
    extern __shared__ f16 lds[];   // [0,32768): A bufs; [32768,65536): B bufs

    const int bid = blockIdx.x;                   // 256 blocks
    const int mt = bid >> 5;                      // 0..7  M-tile
    const int slot = bid & 31;                    // (nt,sk) -> XCD = slot&7
    const int nt = slot & 1;
    const int sk = slot >> 1;                     // 0..15
    const int kt0 = sk * 42 + (sk < 3 ? sk : 3);  // uneven split: 3x43 + 13x42
    const int cnt = 42 + (sk < 3 ? 1 : 0);

    const int tid = threadIdx.x;
    const int wave = tid >> 6, lane = tid & 63;
    const int quad = lane >> 4, m16 = lane & 15;
    const int rsw = m16 & 7;                      // row&7 == m16&7 (bases = 0 mod 8)
    const int wm = (wave & 1) << 6;               // 0 / 64   (row slice in each half)
    const int wn = (wave >> 1) << 5;              // 0/32/64/96 (col slice in each half)

    // per-lane staging source for A (row-major): row = tid>>3, chunk = tid&7,
    // source k-chunk = chunk ^ (row&7)  -> LDS[row][chunk] = A[row][swz chunk]
    const int s_row = tid >> 3, s_ch = tid & 7;
    const f16* A_l = A + (size_t)(mt * 256 + s_row) * K_FC1 + (size_t)kt0 * 64
                       + ((s_ch ^ (s_row & 7)) << 3);
    const f16* Bb = W + (size_t)(nt * KT_TOT + kt0) * TILE_F;

    f32x4 acc[8][4] = {};
    f16x8 a[4][2], bA[2][2], bB[2][2];

#define STAGE_A(BUF, HALF, KI) do {                                            \
    const f16* g_ = A_l + (size_t)(HALF) * 128 * K_FC1 + (size_t)(KI) * 64;    \
    f16* l_ = lds + (BUF) * TILE_F + (HALF) * HALF_F + tid * 8;                \
    __builtin_amdgcn_global_load_lds(                                          \
        (const __attribute__((address_space(1))) void*)g_,                     \
        (__attribute__((address_space(3))) void*)l_, 16, 0, 0);                \
    __builtin_amdgcn_global_load_lds(                                          \
        (const __attribute__((address_space(1))) void*)(g_ + (size_t)64 * K_FC1), \
        (__attribute__((address_space(3))) void*)(l_ + 4096), 16, 0, 0);       \
} while (0)

#define STAGE_B(BUF, HALF, KI) do {                                            \
    const f16* g_ = Bb + (size_t)(KI) * TILE_F + (HALF) * HALF_F + tid * 8;    \
    f16* l_ = lds + 32768 + (BUF) * TILE_F + (HALF) * HALF_F + tid * 8;        \
    __builtin_amdgcn_global_load_lds(                                          \
        (const __attribute__((address_space(1))) void*)g_,                     \
        (__attribute__((address_space(3))) void*)l_, 16, 0, 0);                \
    __builtin_amdgcn_global_load_lds(                                          \
        (const __attribute__((address_space(1))) void*)(g_ + 4096),            \
        (__attribute__((address_space(3))) void*)(l_ + 4096), 16, 0, 0);       \
} while (0)

#define RD_A(MH, BUF) do {                                                     \
    _Pragma("unroll") for (int i2_ = 0; i2_ < 4; ++i2_)                        \
    _Pragma("unroll") for (int kh_ = 0; kh_ < 2; ++kh_)                        \
        a[i2_][kh_] = *(const f16x8*)(lds + (BUF) * TILE_F + (MH) * HALF_F     \
            + (wm + i2_ * 16 + m16) * 64 + (((kh_ * 4 + quad) ^ rsw) << 3));   \
} while (0)

#define RD_B(DST, NH, BUF) do {                                                \
    _Pragma("unroll") for (int j2_ = 0; j2_ < 2; ++j2_)                        \
    _Pragma("unroll") for (int kh_ = 0; kh_ < 2; ++kh_)                        \
        DST[j2_][kh_] = *(const f16x8*)(lds + 32768 + (BUF) * TILE_F           \
            + (NH) * HALF_F                                                    \
            + (wn + j2_ * 16 + m16) * 64 + (((kh_ * 4 + quad) ^ rsw) << 3));   \
} while (0)

#define MMA(IO, JO, BF) do {                                                   \
    _Pragma("unroll") for (int i2_ = 0; i2_ < 4; ++i2_)                        \
    _Pragma("unroll") for (int j2_ = 0; j2_ < 2; ++j2_)                        \
    _Pragma("unroll") for (int kh_ = 0; kh_ < 2; ++kh_)                        \
        acc[(IO) + i2_][(JO) + j2_] = __builtin_amdgcn_mfma_f32_16x16x32_f16(  \
            a[i2_][kh_], BF[j2_][kh_], acc[(IO) + i2_][(JO) + j2_], 0, 0, 0);  \
} while (0)

    // prologue: stage tile 0 into buf 0 (order h0=A0, h1=B0, h2=B1, h3=A1)
    STAGE_A(0, 0, 0);
    STAGE_B(0, 0, 0);
    STAGE_B(0, 1, 0);
    STAGE_A(0, 1, 0);
    asm volatile("s_waitcnt vmcnt(4)" ::: "memory");  // h0,h1 landed
    __builtin_amdgcn_s_barrier();

    #pragma unroll 1
    for (int ti = 0; ti < cnt - 1; ++ti) {
        const int bc = ti & 1, bn = bc ^ 1;
        // ---- P1: quad(Mhalf0, Nhalf0); prefetch next A-half0 (h0')
        RD_A(0, bc); RD_B(bA, 0, bc);
        STAGE_A(bn, 0, ti + 1);
        __builtin_amdgcn_s_barrier();
        __builtin_amdgcn_s_setprio(1);
        MMA(0, 0, bA);
        __builtin_amdgcn_s_setprio(0);
        asm volatile("s_waitcnt vmcnt(4)" ::: "memory");  // h2 (B1) landed
        __builtin_amdgcn_s_barrier();
        // ---- P2: quad(0,1); prefetch next B-half0 (h1')
        RD_B(bB, 1, bc);
        STAGE_B(bn, 0, ti + 1);
        __builtin_amdgcn_s_barrier();
        __builtin_amdgcn_s_setprio(1);
        MMA(0, 2, bB);
        __builtin_amdgcn_s_setprio(0);
        asm volatile("s_waitcnt vmcnt(4)" ::: "memory");  // h3 (A1) landed
        __builtin_amdgcn_s_barrier();
        // ---- P3: quad(1,1); prefetch next B-half1 (h2')
        RD_A(1, bc);
        STAGE_B(bn, 1, ti + 1);
        __builtin_amdgcn_s_barrier();
        __builtin_amdgcn_s_setprio(1);
        MMA(4, 2, bB);
        __builtin_amdgcn_s_setprio(0);
        __builtin_amdgcn_s_barrier();
        // ---- P4: quad(1,0) from regs; prefetch next A-half1 (h3')
        STAGE_A(bn, 1, ti + 1);
        __builtin_amdgcn_s_barrier();
        __builtin_amdgcn_s_setprio(1);
        MMA(4, 0, bA);
        __builtin_amdgcn_s_setprio(0);
        asm volatile("s_waitcnt vmcnt(4)" ::: "memory");  // h0',h1' landed
        __builtin_amdgcn_s_barrier();
    }

    // epilogue tile (no prefetch; drains vmcnt once)
    {
        const int bc = (cnt - 1) & 1;
        RD_A(0, bc); RD_B(bA, 0, bc);
        __builtin_amdgcn_s_setprio(1);
        MMA(0, 0, bA);
        __builtin_amdgcn_s_setprio(0);
        asm volatile("s_waitcnt vmcnt(2)" ::: "memory");  // h2 landed
        __builtin_amdgcn_s_barrier();
        RD_B(bB, 1, bc);
        __builtin_amdgcn_s_setprio(1);
        MMA(0, 2, bB);
        __builtin_amdgcn_s_setprio(0);
        asm volatile("s_waitcnt vmcnt(0)" ::: "memory");  // h3 landed
        __builtin_amdgcn_s_barrier();
        RD_A(1, bc);
        __builtin_amdgcn_s_setprio(1);
        MMA(4, 2, bB);
        MMA(4, 0, bA);
        __builtin_amdgcn_s_setprio(0);
    }

#undef STAGE_A
#undef STAGE_B
#undef RD_A
#undef RD_B
#undef MMA

    // C/D layout: col = lane&15, row = quad*4 + reg. Atomic split-K reduce.
    // acc[i][j]: row half = i>>2, row frag = i&3; col half = j>>1, frag = j&1.
    float* Yb = Ysum + (size_t)(mt * 256) * 512 + nt * 256;
    #pragma unroll
    for (int i = 0; i < 8; ++i) {
        const int row0 = (i >> 2) * 128 + wm + (i & 3) * 16 + quad * 4;
        #pragma unroll
        for (int j = 0; j < 4; ++j) {
            const int col = (j >> 1) * 128 + wn + (j & 1) * 16 + m16;
            #pragma unroll
            for (int r = 0; r < 4; ++r)
                unsafeAtomicAdd(&Yb[(size_t)(row0 + r) * 512 + col], acc[i][j][r]);
        }
    }
}

// ---------------------------------------------------------------------------
// Kernel 4: head = (relu(sum*256+b1)) -> fc2 + sigmoid -> fc3
// 8 samples/block, 128 threads -> 256 blocks per chunk.
// ---------------------------------------------------------------------------
__global__ __launch_bounds__(128) void head_fc23(const float* __restrict__ y1s,
                                                 const float* __restrict__ b1,
                                                 const float* __restrict__ w2,
                                                 const float* __restrict__ b2,
                                                 const float* __restrict__ w3,
                                                 const float* __restrict__ b3,
                                                 float* __restrict__ out, int n0)
{
    __shared__ float Ys[8 * 512];    // 16 KB
    __shared__ float Y2[8 * 128];    // 4 KB
    const int t = threadIdx.x;
    const float4* yb = (const float4*)(y1s + (size_t)blockIdx.x * 8 * 512);
    const float4* b1v = (const float4*)b1;
    for (int i = t; i < 8 * 128; i += 128) {
        float4 s = yb[i];
        float4 bv = b1v[i & 127];
        float4 y;
        y.x = fmaxf(fmaf(s.x, 256.f, bv.x), 0.f);
        y.y = fmaxf(fmaf(s.y, 256.f, bv.y), 0.f);
        y.z = fmaxf(fmaf(s.z, 256.f, bv.z), 0.f);
        y.w = fmaxf(fmaf(s.w, 256.f, bv.w), 0.f);
        ((float4*)Ys)[i] = y;
    }
    __syncthreads();

    float acc[8];
    float bk = b2[t];
    #pragma unroll
    for (int s = 0; s < 8; ++s) acc[s] = bk;
    const float4* wr = (const float4*)(w2 + (size_t)t * 512);
    for (int jc = 0; jc < 128; ++jc) {
        float4 w4 = wr[jc];
        #pragma unroll
        for (int s = 0; s < 8; ++s) {
            float4 y4 = *(const float4*)(Ys + s * 512 + jc * 4);
            acc[s] += w4.x * y4.x + w4.y * y4.y + w4.z * y4.z + w4.w * y4.w;
        }
    }
    #pragma unroll
    for (int s = 0; s < 8; ++s) Y2[s * 128 + t] = 1.0f / (1.0f + expf(-acc[s]));
    __syncthreads();

    if (t < 8) {
        float sm = b3[0];
        #pragma unroll 4
        for (int k = 0; k < 128; ++k) sm += Y2[t * 128 + k] * w3[k];
        out[n0 + blockIdx.x * 8 + t] = sm;
    }
}

// ---------------------------------------------------------------------------
extern "C" void kernel_launch(void* const* d_in, const int* in_sizes, int n_in,
                              void* d_out, int out_size, void* d_ws, size_t ws_size,
                              hipStream_t stream)
{
    const float* data = (const float*)d_in[0];
    const float* bn_g = (const float*)d_in[1];
    const float* bn_b = (const float*)d_in[2];
    const float* bn_m = (const float*)d_in[3];
    const float* bn_v = (const float*)d_in[4];
    const float* cw   = (const float*)d_in[5];
    const float* cb   = (const float*)d_in[6];
    const float* fc1w = (const float*)d_in[7];
    const float* fc1b = (const float*)d_in[8];
    const float* fc2w = (const float*)d_in[9];
    const float* fc2b = (const float*)d_in[10];
    const float* fc3w = (const float*)d_in[11];
    const float* fc3b = (const float*)d_in[12];
    float* out = (float*)d_out;

    // workspace layout (total ~225.6 MB, known-safe)
    const size_t A16_BYTES = (size_t)CHUNK * K_FC1 * 2;       // 176,947,200
    const size_t W16_BYTES = (size_t)512 * K_FC1 * 2;         //  44,236,800
    const size_t Y1_BYTES  = (size_t)CHUNK * 512 * 4;         //   4,194,304
    if (ws_size < A16_BYTES + W16_BYTES + Y1_BYTES) return;

    char* ws = (char*)d_ws;
    f16*   A16 = (f16*)ws;
    f16*   W16 = (f16*)(ws + A16_BYTES);
    float* y1s = (float*)(ws + A16_BYTES + W16_BYTES);

    // one-time opt-in for 128 KiB dynamic LDS (gfx950 has 160 KiB/CU)
    static int smem_set = 0;
    if (!smem_set) {
        hipFuncSetAttribute(reinterpret_cast<const void*>(gemm_fc1),
                            hipFuncAttributeMaxDynamicSharedMemorySize, 131072);
        smem_set = 1;
    }

    retile_w<<<2 * KT_TOT, 256, 0, stream>>>(fc1w, W16);

    for (int c = 0; c < 2; ++c) {
        int n0 = c * CHUNK;
        hipMemsetAsync(y1s, 0, Y1_BYTES, stream);
        stage_a<<<CHUNK, 256, 0, stream>>>(data, bn_g, bn_b, bn_m, bn_v, cw, cb, A16, n0);
        gemm_fc1<<<256, 512, 131072, stream>>>(A16, W16, y1s);
        head_fc23<<<CHUNK / 8, 128, 0, stream>>>(y1s, fc1b, fc2w, fc2b, fc3w, fc3b, out, n0);
    }
}